// Round 14
// baseline (1829.096 us; speedup 1.0000x reference)
//
#include <hip/hip_runtime.h>

#define BB 16
#define NN 8192
#define SS 512
#define N3 (3 * NN)  // 24576 elements per batch per tensor
#define KD 14        // per-lane KNN list depth (see k_tail comment)

typedef unsigned short u16;
typedef unsigned int u32;
typedef unsigned long long u64;
typedef float v2f __attribute__((ext_vector_type(2)));

// Packed fp32 ops (VOP3P, 2 values/inst). Per-half rounding is IEEE rn —
// bit-identical to scalar __fadd_rn/__fmul_rn.
__device__ __forceinline__ v2f pk_add(v2f a, v2f b) {
  v2f r;
  asm("v_pk_add_f32 %0, %1, %2" : "=v"(r) : "v"(a), "v"(b));
  return r;
}
__device__ __forceinline__ v2f pk_mul(v2f a, v2f b) {
  v2f r;
  asm("v_pk_mul_f32 %0, %1, %2" : "=v"(r) : "v"(a), "v"(b));
  return r;
}
__device__ __forceinline__ v2f pk_fma(v2f a, v2f b, v2f c) {
  v2f r;
  asm("v_pk_fma_f32 %0, %1, %2, %3" : "=v"(r) : "v"(a), "v"(b), "v"(c));
  return r;
}

template <int CTRL>
__device__ __forceinline__ float dpp_maxf(float x) {
  // old=0 is the identity for max of non-negative values
  int m = __builtin_amdgcn_update_dpp(0, __float_as_int(x), CTRL, 0xf, 0xf, false);
  return fmaxf(x, __int_as_float(m));
}
template <int CTRL>
__device__ __forceinline__ u32 dpp_maxu(u32 x) {
  u32 m = (u32)__builtin_amdgcn_update_dpp(0, (int)x, CTRL, 0xf, 0xf, false);
  return (x > m) ? x : m;
}

// ---------------------------------------------------------------------------
// K1: farthest point sampling — EXACT r13 version (best measured 543 us).
// One barrier/iter; wave-local find pass vs readlane-broadcast wave max;
// lane63 publishes one packed (dist<<32|NN-idx) key; LDS-staged point cloud
// for the center broadcast read. Bit-exact vs numpy (rn ops, np.argmax
// lowest-index tie-break).
// ---------------------------------------------------------------------------
__global__ __attribute__((amdgpu_flat_work_group_size(256, 256),
                          amdgpu_waves_per_eu(1, 1)))
void k_fps(const float* __restrict__ xyz, float* __restrict__ out_kp) {
  __shared__ float sxyz[NN * 3];  // [idx][x,y,z]
  __shared__ int sIdx[SS];
  __shared__ u64 rkey[2][4];
  int b = blockIdx.x, t = threadIdx.x;
  const float* base = xyz + b * N3;
  v2f px[16], py[16], pz[16], dm[16];
#pragma unroll
  for (int j = 0; j < 16; ++j) {
    int n0 = j * 512 + t, n1 = n0 + 256;  // coalesced, disjoint cover [0,8192)
    px[j] = v2f{base[n0], base[n1]};
    py[j] = v2f{base[NN + n0], base[NN + n1]};
    pz[j] = v2f{base[2 * NN + n0], base[2 * NN + n1]};
    dm[j] = v2f{1e10f, 1e10f};
    sxyz[n0 * 3 + 0] = px[j].x;  // stage AoS copy for center re-loads
    sxyz[n0 * 3 + 1] = py[j].x;
    sxyz[n0 * 3 + 2] = pz[j].x;
    sxyz[n1 * 3 + 0] = px[j].y;
    sxyz[n1 * 3 + 1] = py[j].y;
    sxyz[n1 * 3 + 2] = pz[j].y;
  }
#pragma unroll
  for (int j = 0; j < 16; ++j) {
    // Opaque def: blocks rematerialization of the global loads.
    asm volatile("" : "+v"(px[j]), "+v"(py[j]), "+v"(pz[j]));
  }
  // staging writes become visible at iter-0's barrier, before first LDS read
  float cx = base[0], cy = base[NN], cz = base[2 * NN];
  int far = 0;
  int lane = t & 63, w = t >> 6;
  u32 tb = (u32)(NN - t);  // candidate base: cand = NN - gidx (1..8192; 0=none)
  for (int it = 0; it < SS; ++it) {
    if (t == 0) sIdx[it] = far;  // scan emits carry BEFORE update: idx[0]=0
    // negated center, broadcast to both halves (a + (-c) == a - c exactly)
    v2f ncx = v2f{-cx, -cx}, ncy = v2f{-cy, -cy}, ncz = v2f{-cz, -cz};
    float vmax = 0.0f;
#pragma unroll
    for (int j = 0; j < 16; ++j) {
      v2f dx = pk_add(px[j], ncx);
      v2f dy = pk_add(py[j], ncy);
      v2f dz = pk_add(pz[j], ncz);
      v2f xx = pk_mul(dx, dx);
      v2f yy = pk_mul(dy, dy);
      v2f s = pk_add(xx, yy);
      v2f zz = pk_mul(dz, dz);
      v2f d = pk_add(s, zz);  // ((dx^2+dy^2)+dz^2), numpy tree per half
      float a0 = fminf(dm[j].x, d.x);
      float a1 = fminf(dm[j].y, d.y);
      dm[j].x = a0;
      dm[j].y = a1;
      vmax = fmaxf(vmax, fmaxf(a0, a1));  // max3-foldable
    }
    // wave max (single chain, distances >= 0), then SALU broadcast
    vmax = dpp_maxf<0x111>(vmax);  // row_shr:1
    vmax = dpp_maxf<0x112>(vmax);  // row_shr:2
    vmax = dpp_maxf<0x114>(vmax);  // row_shr:4
    vmax = dpp_maxf<0x118>(vmax);  // row_shr:8
    vmax = dpp_maxf<0x142>(vmax);  // row_bcast:15
    vmax = dpp_maxf<0x143>(vmax);  // row_bcast:31 -> lane63 = wave max
    float wv = __int_as_float(__builtin_amdgcn_readlane(__float_as_int(vmax), 63));
    // find pass vs WAVE max: exact bit-equality (wv IS one of this wave's dm
    // values); descending gidx order so the LAST write = lowest gidx.
    u32 cand = 0;
#pragma unroll
    for (int j = 15; j >= 0; --j) {
      u32 v1 = tb - (u32)(j * 512 + 256);  // cand for .y half (higher gidx)
      u32 v0 = tb - (u32)(j * 512);        // cand for .x half
      cand = (dm[j].y == wv) ? v1 : cand;
      cand = (dm[j].x == wv) ? v0 : cand;
    }
    cand = dpp_maxu<0x111>(cand);
    cand = dpp_maxu<0x112>(cand);
    cand = dpp_maxu<0x114>(cand);
    cand = dpp_maxu<0x118>(cand);
    cand = dpp_maxu<0x142>(cand);
    cand = dpp_maxu<0x143>(cand);  // lane63 = wave best (max cand = min gidx)
    int pb = it & 1;  // parity double-buffer: safe with one barrier/iter
    if (lane == 63) rkey[pb][w] = ((u64)__float_as_uint(wv) << 32) | cand;
    __syncthreads();  // the only barrier per iteration
    u64 k0 = rkey[pb][0], k1 = rkey[pb][1];
    u64 k2 = rkey[pb][2], k3 = rkey[pb][3];
    u64 k01 = (k0 > k1) ? k0 : k1;
    u64 k23 = (k2 > k3) ? k2 : k3;
    u64 kg = (k01 > k23) ? k01 : k23;
    far = NN - (int)(u32)(kg & 0xffffffffu);
    // broadcast ds_read of the winner's coords (all lanes same address)
    cx = sxyz[far * 3 + 0];
    cy = sxyz[far * 3 + 1];
    cz = sxyz[far * 3 + 2];
  }
  __syncthreads();
  for (int i = t; i < SS; i += 256) {
    int id = sIdx[i];
    out_kp[b * 1536 + i] = base[id];  // exact fp32 copies
    out_kp[b * 1536 + SS + i] = base[NN + id];
    out_kp[b * 1536 + 2 * SS + i] = base[2 * NN + id];
  }
}

// ---------------------------------------------------------------------------
// K2 (fused tail): knn + base MLP + 3 ms MLPs in ONE kernel. Block = 4 waves
// = 4 consecutive rows (same batch). Phase 1: wave w computes its row's
// sorted top-24 (KD=14 per-lane depth: top-24 ids ~uniform mod 64, P(lane
// holds >=15) < 1e-15) into LDS — global knn ws eliminated. Phase 2: base
// MLP (feat 6 -> 64 relu -> 128, max over 16). Phase 3: per scale, rel-xyz
// MLP (3 -> 64 relu -> 128, max over kk). h2 dots use v_pk_fma_f32 on
// (adjacent h1 pair) x (adjacent weight pair), final .x+.y — reassociation
// OK under the 2% tolerance. waves_per_eu(1,1): 256-VGPR budget keeps the
// 64-pair weight arrays in true VGPRs (r5-r8 lesson: default budget spills
// them). Fusion removes 2 dispatch tails, halves weight re-loads, and
// reuses the knn result directly from LDS.
// ---------------------------------------------------------------------------
__global__ __attribute__((amdgpu_flat_work_group_size(256, 256),
                          amdgpu_waves_per_eu(1, 1)))
void k_tail(const float* __restrict__ xyz, const float* __restrict__ pts,
            const float* __restrict__ kp, const float* __restrict__ W1,
            const float* __restrict__ b1, const float* __restrict__ W2,
            const float* __restrict__ b2, const float* __restrict__ msW1,
            const float* __restrict__ msb1, const float* __restrict__ msW2,
            const float* __restrict__ msb2, float* __restrict__ out) {
  __shared__ u16 sknn[4][24];
  __shared__ float sW1T[6 * 64];  // base W1 [c][o]
  __shared__ float sb1[64];
  __shared__ float sW1m[3 * 64];  // ms W1 [c][o], reloaded per scale
  __shared__ float sb1m[64];
  __shared__ float sfeat[4][16 * 6];  // base 16k x 6c; ms reuse 24k x 3c (72)
  __shared__ float sh1[4][24 * 64];
  int t = threadIdx.x, lane = t & 63, w = t >> 6;
  int row0 = blockIdx.x * 4;   // 4-aligned -> all 4 rows in one batch
  int b = row0 >> 9;
  int s0 = row0 & (SS - 1);
  const float* base = xyz + b * N3;
  const float* kpb = kp + b * 1536;
  float* outb = out + 24576 + b * 262144;

  // stage base W1/b1 (visible after the phase-1 barrier)
  for (int i = t; i < 384; i += 256) {
    int o = i / 6, c = i - o * 6;
    sW1T[c * 64 + o] = W1[i];
  }
  if (t < 64) sb1[t] = b1[t];

  // ---- phase 1: sorted top-24 for row s0+w (dist asc, idx asc — lax.top_k
  // stable tie-break). d = (|a|^2+|q|^2) - 2*dot, rn ops = numpy tree.
  {
    int s = s0 + w;
    float ax = kpb[s], ay = kpb[SS + s], az = kpb[2 * SS + s];
    float aw = __fadd_rn(__fadd_rn(__fmul_rn(ax, ax), __fmul_rn(ay, ay)),
                         __fmul_rn(az, az));
    u64 arr[KD];
#pragma unroll
    for (int i = 0; i < KD; ++i) arr[i] = ~0ull;
    for (int c = 0; c < 128; ++c) {
      int n = c * 64 + lane;
      float qx = base[n], qy = base[NN + n], qz = base[2 * NN + n];
      float qw = __fadd_rn(__fadd_rn(__fmul_rn(qx, qx), __fmul_rn(qy, qy)),
                           __fmul_rn(qz, qz));
      float dot = __fadd_rn(__fadd_rn(__fmul_rn(ax, qx), __fmul_rn(ay, qy)),
                            __fmul_rn(az, qz));
      float d = __fsub_rn(__fadd_rn(aw, qw), __fmul_rn(2.0f, dot));
      u32 ub = __float_as_uint(d);
      ub ^= (ub & 0x80000000u) ? 0xFFFFFFFFu : 0x80000000u;  // order-preserving
      u64 key = ((u64)ub << 32) | (u32)n;
      if (key < arr[KD - 1]) {  // branchless descending insertion (arr asc)
#pragma unroll
        for (int i = KD - 1; i >= 1; --i) {
          u64 am = arr[i - 1];
          arr[i] = (am > key) ? am : ((arr[i] > key) ? key : arr[i]);
        }
        if (arr[0] > key) arr[0] = key;
      }
    }
    // merge 64 sorted lists: 24 x (wave-min of heads, winner pops)
    for (int it = 0; it < 24; ++it) {
      u64 m = arr[0];
#pragma unroll
      for (int off = 1; off < 64; off <<= 1) {
        u64 o = __shfl_xor(m, off, 64);
        m = (o < m) ? o : m;
      }
      if (lane == it) sknn[w][it] = (u16)(m & 0xFFFFu);
      if (arr[0] == m) {
#pragma unroll
        for (int i = 0; i < KD - 1; ++i) arr[i] = arr[i + 1];
        arr[KD - 1] = ~0ull;
      }
    }
  }
  __syncthreads();

  // ---- phase 2: base MLP, 4 rows
  for (int i = t; i < 384; i += 256) {  // 4 rows x 16 k x 6 c
    int rr = i / 96, rem = i - rr * 96, k = rem / 6, c = rem - k * 6;
    int s = s0 + rr;
    int id = sknn[rr][k];  // first 16 of the sorted 24 = base KNN
    float val;
    if (c < 3) {
      val = __fsub_rn(base[c * NN + id], kpb[c * SS + s]);
    } else {
      val = pts[b * N3 + (c - 3) * NN + id];
    }
    sfeat[rr][k * 6 + c] = val;
  }
  __syncthreads();
#pragma unroll
  for (int m = 0; m < 16; ++m) {  // 4 rows x 1024 h1 entries / 256 thr
    int u = m * 256 + t;
    int rr = u >> 10, rem = u & 1023, k = rem >> 6, o = rem & 63;
    float acc = sb1[o];
#pragma unroll
    for (int c = 0; c < 6; ++c) acc = fmaf(sfeat[rr][k * 6 + c], sW1T[c * 64 + o], acc);
    sh1[rr][k * 64 + o] = fmaxf(acc, 0.f);
  }
  __syncthreads();
  {
    const v2f* W2v = (const v2f*)W2;
    v2f wA[32], wB[32];
#pragma unroll
    for (int j = 0; j < 32; ++j) {
      wA[j] = W2v[lane * 32 + j];
      wB[j] = W2v[(lane + 64) * 32 + j];
    }
    float bestA = -1e30f, bestB = -1e30f;
#pragma unroll
    for (int k = 0; k < 16; ++k) {
      const v2f* h2 = (const v2f*)&sh1[w][k * 64];  // wave-uniform broadcast
      v2f aA = v2f{0.f, 0.f}, aB = v2f{0.f, 0.f};
#pragma unroll
      for (int j = 0; j < 32; ++j) {
        v2f hv = h2[j];
        aA = pk_fma(hv, wA[j], aA);
        aB = pk_fma(hv, wB[j], aB);
      }
      bestA = fmaxf(bestA, aA.x + aA.y);
      bestB = fmaxf(bestB, aB.x + aB.y);
    }
    int s = s0 + w;
    outb[lane * 512 + s] = bestA + b2[lane];
    outb[(lane + 64) * 512 + s] = bestB + b2[lane + 64];
  }

  // ---- phase 3: ms scales
  for (int scale = 0; scale < 3; ++scale) {
    int kk = 8 * (scale + 1);
    __syncthreads();  // protect sh1/sfeat/sW1m from previous-phase reads
    for (int i = t; i < 192; i += 256) {
      int o = i / 3, c = i - o * 3;
      sW1m[c * 64 + o] = msW1[scale * 192 + i];
    }
    if (t < 64) sb1m[t] = msb1[scale * 64 + t];
    int nfeat = 4 * kk * 3;
    int kk3 = kk * 3;
    for (int i = t; i < nfeat; i += 256) {  // 4 rows x kk k x 3 c
      int rr = i / kk3, rem = i - rr * kk3, k = rem / 3, c = rem - k * 3;
      int s = s0 + rr;
      int id = sknn[rr][k];
      sfeat[rr][k * 3 + c] = __fsub_rn(base[c * NN + id], kpb[c * SS + s]);
    }
    __syncthreads();
    for (int rr = 0; rr < 4; ++rr) {
      for (int u = t; u < kk * 64; u += 256) {
        int k = u >> 6, o = u & 63;
        float acc = sb1m[o];
        acc = fmaf(sfeat[rr][k * 3 + 0], sW1m[o], acc);
        acc = fmaf(sfeat[rr][k * 3 + 1], sW1m[64 + o], acc);
        acc = fmaf(sfeat[rr][k * 3 + 2], sW1m[128 + o], acc);
        sh1[rr][k * 64 + o] = fmaxf(acc, 0.f);
      }
    }
    __syncthreads();
    const v2f* Wv = (const v2f*)(msW2 + scale * 8192);
    v2f wA[32], wB[32];
#pragma unroll
    for (int j = 0; j < 32; ++j) {
      wA[j] = Wv[lane * 32 + j];
      wB[j] = Wv[(lane + 64) * 32 + j];
    }
    float bestA = -1e30f, bestB = -1e30f;
    for (int k = 0; k < kk; ++k) {  // kk uniform -> no divergence
      const v2f* h2 = (const v2f*)&sh1[w][k * 64];
      v2f aA = v2f{0.f, 0.f}, aB = v2f{0.f, 0.f};
#pragma unroll
      for (int j = 0; j < 32; ++j) {
        v2f hv = h2[j];
        aA = pk_fma(hv, wA[j], aA);
        aB = pk_fma(hv, wB[j], aB);
      }
      bestA = fmaxf(bestA, aA.x + aA.y);
      bestB = fmaxf(bestB, aB.x + aB.y);
    }
    int s = s0 + w;
    int co = 128 * (scale + 1);
    outb[(co + lane) * 512 + s] = bestA + msb2[scale * 128 + lane];
    outb[(co + lane + 64) * 512 + s] = bestB + msb2[scale * 128 + lane + 64];
  }
}

// ---------------------------------------------------------------------------
extern "C" void kernel_launch(void* const* d_in, const int* in_sizes, int n_in,
                              void* d_out, int out_size, void* d_ws, size_t ws_size,
                              hipStream_t stream) {
  const float* xyz = (const float*)d_in[0];    // l0_xyz  [B,3,N] f32
  const float* pts = (const float*)d_in[1];    // l0_points
  const float* sa_W1 = (const float*)d_in[2];  // [64,6]
  const float* sa_b1 = (const float*)d_in[3];  // [64]
  const float* sa_W2 = (const float*)d_in[4];  // [128,64]
  const float* sa_b2 = (const float*)d_in[5];  // [128]
  const float* ms_W1 = (const float*)d_in[6];  // [3,64,3]
  const float* ms_b1 = (const float*)d_in[7];  // [3,64]
  const float* ms_W2 = (const float*)d_in[8];  // [3,128,64]
  const float* ms_b2 = (const float*)d_in[9];  // [3,128]
  float* out = (float*)d_out;
  const float* kp = (const float*)d_out;  // keypoints written by k_fps

  k_fps<<<BB, 256, 0, stream>>>(xyz, out);
  k_tail<<<(BB * SS) / 4, 256, 0, stream>>>(xyz, pts, kp, sa_W1, sa_b1, sa_W2,
                                            sa_b2, ms_W1, ms_b1, ms_W2, ms_b2, out);
}